// Round 7
// baseline (498.412 us; speedup 1.0000x reference)
//
#include <hip/hip_runtime.h>
#include <math.h>

#define N_COLL 200000

typedef const float* fp;
typedef __attribute__((ext_vector_type(8))) short bf16x8;
typedef __attribute__((ext_vector_type(4))) float f32x4;
typedef __attribute__((ext_vector_type(4))) short s16x4;

// ---------------- workspace layout (float offsets) ----------------
#define WS_UP    0         // 64
#define WS_US    64        // 64
#define WS_UW    128       // 32
#define WS_HP    160       // 32
#define WS_HV    192       // 32
#define WS_HR    224       // 32
#define WS_XU    384       // 128
#define WS_W1    512       // 14336
#define WS_W2    14848     // 2048
#define WS_W3    16896     // 32
#define WS_NEIGH 16928     // 16 banks x 128 (zeroed)
#define WS_CSUM  18976     // 32 banks x 132 (zeroed)
#define WS_BAR   23200     // 8 u32 barrier counters (zeroed)
#define WS_GX    23552     // 2048*128 f32
#define WS_HT1   285696    // 128*2048 u16
#define WS_F1G   416768    // 4*2048
#define WS_F2G   424960    // 4*2048
#define WS_HCAT  433152    // 2048*128 f32
#define WS_HT2   695296    // 128*2048 u16
#define WS_F1O   826368    // 2048
#define WS_F2O   828416    // 2048
#define WS_MASK  830464    // 2048*64 u32
// end 961536 floats = 3.85 MB

__device__ __forceinline__ float celu1(float x){
    return fmaxf(x, 0.f) + __expf(fminf(x, 0.f)) - 1.f;   // branchless elu
}
__device__ __forceinline__ float rl(float x, int k){
    return __int_as_float(__builtin_amdgcn_readlane(__float_as_int(x), k));
}
__device__ __forceinline__ short f2bf(float f){
    return (short)(__float_as_uint(f) >> 16);
}
__device__ __forceinline__ bf16x8 pack8(f32x4 a, f32x4 b){
    bf16x8 r;
    r[0]=f2bf(a[0]); r[1]=f2bf(a[1]); r[2]=f2bf(a[2]); r[3]=f2bf(a[3]);
    r[4]=f2bf(b[0]); r[5]=f2bf(b[1]); r[6]=f2bf(b[2]); r[7]=f2bf(b[3]);
    return r;
}

#define GRID_N 512u
// device-scope grid barrier: release fence + count, spin, acquire fence.
__device__ __forceinline__ void gbar(float* ws, int which){
    unsigned* c = (unsigned*)(ws + WS_BAR) + which;
    __syncthreads();
    if (threadIdx.x == 0){
        __threadfence();                     // release: drain writes to coherence point
        atomicAdd(c, 1u);
        while (atomicAdd(c, 0u) < GRID_N) __builtin_amdgcn_s_sleep(8);
        __threadfence();                     // acquire: invalidate stale L1/L2
    }
    __syncthreads();
}

// ======================= THE MEGA-KERNEL =======================
// P0: coll(0-383) | mask+tiny(384-447) | gx(448-511)
// P1: l1_proj MFMA(0-127) | fuse_user(128)
// P2: attend1(all 512)
// P3: l2_proj MFMA(0-127) | hyper_w(128-192)
// P4: attend2(0-127)
// P5: final(0)
__global__ __launch_bounds__(256, 2) void mega(
    fp xup, fp xus, fp xuw, fp Xcp, fp Xcs,
    fp xhp, fp xhv, fp xhr, fp Xnp, fp Xns, const int* __restrict__ adj,
    fp Wup, fp bup, fp Wus, fp bus, fp Wuw, fp buw, fp vw,
    fp Wf1, fp bf1, fp Wf2, fp bf2,
    fp Wm1, fp bm1, fp Wm2, fp bm2, fp Wm3, fp bm3,
    fp Whp, fp bhp, fp Whv, fp bhv, fp Whr, fp bhr,
    fp Wg, fp ag, fp Wo, fp ao,
    float* ws, float* out)
{
    __shared__ float smem[8512];   // 34 KB: max over phases (attend2)
    const int t = threadIdx.x;
    const int b = blockIdx.x;
    const int lane = t & 63, wv = t >> 6;
    const int q = lane >> 4, c16 = lane & 15;

    // =================== P0 ===================
    if (b < 384){
        // ---- colleague bf16-MFMA pass, B-frags direct from global ----
        float* sRed = smem;   // 528
        bf16x8 B[2][2][4];
        float bias[8], vv[8];
        #pragma unroll
        for (int mat = 0; mat < 2; ++mat){
            fp W = mat ? Wus : Wup;
            #pragma unroll
            for (int ks = 0; ks < 2; ++ks)
                #pragma unroll
                for (int ct = 0; ct < 4; ++ct){
                    bf16x8 f;
                    #pragma unroll
                    for (int j = 0; j < 8; ++j)
                        f[j] = f2bf(W[(ks*32 + q*8 + j)*64 + ct*16 + c16]);
                    B[mat][ks][ct] = f;
                }
        }
        #pragma unroll
        for (int tt = 0; tt < 8; ++tt){
            int gcol = tt*16 + c16;
            bias[tt] = (tt < 4) ? bup[gcol] : bus[gcol-64];
            vv[tt]   = vw[128 + gcol];
        }
        const int wave = b*4 + wv;      // 0..1535
        float accw[8] = {0,0,0,0,0,0,0,0};
        float accl = 0.f;
        int rt = wave;
        f32x4 L[8];
        {
            int row = rt*16 + c16;
            const float* xp = Xcp + row*64 + q*8;
            const float* xs = Xcs + row*64 + q*8;
            L[0]=*(const f32x4*)(xp);    L[1]=*(const f32x4*)(xp+4);
            L[2]=*(const f32x4*)(xp+32); L[3]=*(const f32x4*)(xp+36);
            L[4]=*(const f32x4*)(xs);    L[5]=*(const f32x4*)(xs+4);
            L[6]=*(const f32x4*)(xs+32); L[7]=*(const f32x4*)(xs+36);
        }
        while (rt < 12500){
            int nrt = rt + 1536;
            f32x4 N[8];
            if (nrt < 12500){
                int row = nrt*16 + c16;
                const float* xp = Xcp + row*64 + q*8;
                const float* xs = Xcs + row*64 + q*8;
                N[0]=*(const f32x4*)(xp);    N[1]=*(const f32x4*)(xp+4);
                N[2]=*(const f32x4*)(xp+32); N[3]=*(const f32x4*)(xp+36);
                N[4]=*(const f32x4*)(xs);    N[5]=*(const f32x4*)(xs+4);
                N[6]=*(const f32x4*)(xs+32); N[7]=*(const f32x4*)(xs+36);
            }
            bf16x8 Ap0 = pack8(L[0],L[1]);
            bf16x8 Ap1 = pack8(L[2],L[3]);
            bf16x8 As0 = pack8(L[4],L[5]);
            bf16x8 As1 = pack8(L[6],L[7]);
            float cel[8][4];
            float logit[4] = {0,0,0,0};
            #pragma unroll
            for (int tt = 0; tt < 8; ++tt){
                int ct = tt & 3;
                f32x4 c = {0.f,0.f,0.f,0.f};
                if (tt < 4){
                    c = __builtin_amdgcn_mfma_f32_16x16x32_bf16(Ap0, B[0][0][ct], c, 0,0,0);
                    c = __builtin_amdgcn_mfma_f32_16x16x32_bf16(Ap1, B[0][1][ct], c, 0,0,0);
                } else {
                    c = __builtin_amdgcn_mfma_f32_16x16x32_bf16(As0, B[1][0][ct], c, 0,0,0);
                    c = __builtin_amdgcn_mfma_f32_16x16x32_bf16(As1, B[1][1][ct], c, 0,0,0);
                }
                #pragma unroll
                for (int r = 0; r < 4; ++r){
                    float v = celu1(c[r] + bias[tt]);
                    cel[tt][r] = v;
                    logit[r] = fmaf(v, vv[tt], logit[r]);
                }
            }
            #pragma unroll
            for (int d = 1; d < 16; d <<= 1){
                #pragma unroll
                for (int r = 0; r < 4; ++r) logit[r] += __shfl_xor(logit[r], d);
            }
            float p[4];
            #pragma unroll
            for (int r = 0; r < 4; ++r){ p[r] = __expf(logit[r]); accl += p[r]; }
            #pragma unroll
            for (int tt = 0; tt < 8; ++tt)
                #pragma unroll
                for (int r = 0; r < 4; ++r) accw[tt] = fmaf(p[r], cel[tt][r], accw[tt]);
            #pragma unroll
            for (int i = 0; i < 8; ++i) L[i] = N[i];
            rt = nrt;
        }
        #pragma unroll
        for (int tt = 0; tt < 8; ++tt){
            accw[tt] += __shfl_xor(accw[tt], 16);
            accw[tt] += __shfl_xor(accw[tt], 32);
        }
        accl += __shfl_xor(accl, 16);
        accl += __shfl_xor(accl, 32);
        if (q == 0){
            #pragma unroll
            for (int tt = 0; tt < 8; ++tt) sRed[wv*132 + tt*16 + c16] = accw[tt];
        }
        if (lane == 0) sRed[wv*132 + 128] = accl;
        __syncthreads();
        if (t < 129){
            float s = sRed[t] + sRed[132+t] + sRed[264+t] + sRed[396+t];
            atomicAdd(ws + WS_CSUM + (b & 31)*132 + t, s);
        }
    } else if (b < 448){
        // ---- adjacency -> bitmask (64 blocks x 2048 words) ----
        unsigned* mb = (unsigned*)(ws + WS_MASK);
        #pragma unroll
        for (int s = 0; s < 8; ++s){
            int idx = (b-384)*2048 + s*256 + t;
            const int* a = adj + (idx>>6)*2048 + (idx&63)*32;
            unsigned bits = 0u;
            #pragma unroll 8
            for (int j = 0; j < 32; ++j) bits |= (a[j] > 0 ? 1u : 0u) << j;
            mb[idx] = bits;
        }
        if (b == 384){
            // ---- tiny user/house embeddings ----
            if (t < 64){
                float acc = bup[t];
                for (int k = 0; k < 64; ++k) acc = fmaf(xup[k], Wup[k*64+t], acc);
                ws[WS_UP+t] = celu1(acc);
            } else if (t < 128){
                int j = t-64; float acc = bus[j];
                for (int k = 0; k < 64; ++k) acc = fmaf(xus[k], Wus[k*64+j], acc);
                ws[WS_US+j] = celu1(acc);
            } else if (t < 160){
                int j = t-128; float acc = buw[j];
                for (int k = 0; k < 32; ++k) acc = fmaf(xuw[k], Wuw[k*32+j], acc);
                ws[WS_UW+j] = celu1(acc);
            } else if (t < 192){
                int j = t-160; float acc = bhp[j];
                for (int k = 0; k < 32; ++k) acc = fmaf(xhp[k], Whp[k*32+j], acc);
                ws[WS_HP+j] = celu1(acc);
            } else if (t < 224){
                int j = t-192; float acc = bhv[j];
                for (int k = 0; k < 32; ++k) acc = fmaf(xhv[k], Whv[k*32+j], acc);
                ws[WS_HV+j] = celu1(acc);
            } else {
                int j = t-224; float acc = bhr[j];
                for (int k = 0; k < 32; ++k) acc = fmaf(xhr[k], Whr[k*32+j], acc);
                ws[WS_HR+j] = celu1(acc);
            }
        }
    } else {
        // ---- neighborhood node embeddings gx (64 blocks, 8 rows/wave) ----
        float* sWp = smem;          // 4096
        float* sWs = smem + 4096;   // 4096
        float* sbp = smem + 8192;   // 64
        float* sbs = smem + 8256;   // 64
        for (int i = t; i < 4096; i += 256){ sWp[i] = Wup[i]; sWs[i] = Wus[i]; }
        if (t < 64){ sbp[t]=bup[t]; sbs[t]=bus[t]; }
        __syncthreads();
        int wave = ((b-448)<<2) | wv;            // 0..255
        for (int r = wave; r < 2048; r += 256){
            float xp = Xnp[(r<<6)+lane], xs = Xns[(r<<6)+lane];
            float cp = sbp[lane], cs = sbs[lane];
            #pragma unroll 8
            for (int k = 0; k < 64; ++k){
                cp = fmaf(rl(xp,k), sWp[(k<<6)+lane], cp);
                cs = fmaf(rl(xs,k), sWs[(k<<6)+lane], cs);
            }
            ws[WS_GX + (r<<7) + lane]      = celu1(cp);
            ws[WS_GX + (r<<7) + 64 + lane] = celu1(cs);
        }
    }
    gbar(ws, 0);

    // =================== P1 ===================
    if (b < 128){
        // ---- l1 projection via MFMA: block = 16 rows, wave = head ----
        int rt = b, w = wv;
        bf16x8 A[4];
        const float* gxr = ws + WS_GX + (rt*16 + c16)*128;
        #pragma unroll
        for (int kt = 0; kt < 4; ++kt)
            A[kt] = pack8(*(const f32x4*)(gxr + kt*32 + q*8),
                          *(const f32x4*)(gxr + kt*32 + q*8 + 4));
        unsigned short* ht = (unsigned short*)(ws + WS_HT1);
        float f1p[4] = {0,0,0,0}, f2p[4] = {0,0,0,0};
        #pragma unroll
        for (int ct = 0; ct < 2; ++ct){
            int g = ct*16 + c16;
            f32x4 c = {0,0,0,0};
            #pragma unroll
            for (int kt = 0; kt < 4; ++kt){
                bf16x8 Bf;
                #pragma unroll
                for (int j = 0; j < 8; ++j)
                    Bf[j] = f2bf(Wg[w*4096 + (kt*32 + q*8 + j)*32 + g]);
                c = __builtin_amdgcn_mfma_f32_16x16x32_bf16(A[kt], Bf, c, 0,0,0);
            }
            int col = w*32 + g;
            s16x4 pk;
            pk[0]=f2bf(c[0]); pk[1]=f2bf(c[1]); pk[2]=f2bf(c[2]); pk[3]=f2bf(c[3]);
            *(s16x4*)(ht + col*2048 + rt*16 + q*4) = pk;
            float aga = ag[w*64 + g], agb = ag[w*64 + 32 + g];
            #pragma unroll
            for (int r = 0; r < 4; ++r){
                f1p[r] = fmaf(c[r], aga, f1p[r]);
                f2p[r] = fmaf(c[r], agb, f2p[r]);
            }
        }
        #pragma unroll
        for (int d = 1; d < 16; d <<= 1){
            #pragma unroll
            for (int r = 0; r < 4; ++r){
                f1p[r] += __shfl_xor(f1p[r], d);
                f2p[r] += __shfl_xor(f2p[r], d);
            }
        }
        if (c16 == 0){
            #pragma unroll
            for (int r = 0; r < 4; ++r){
                ws[WS_F1G + (w<<11) + rt*16 + q*4 + r] = f1p[r];
                ws[WS_F2G + (w<<11) + rt*16 + q*4 + r] = f2p[r];
            }
        }
    } else if (b == 128){
        // ---- user fusion MLP ----
        float* fu  = smem;        // 288
        float* hid = smem + 288;  // 256
        float* cs  = smem + 544;  // 129
        if (t < 129){
            float s = 0.f;
            #pragma unroll
            for (int k = 0; k < 32; ++k) s += ws[WS_CSUM + k*132 + t];
            cs[t] = s;
        }
        if (t < 64)       fu[t] = ws[WS_UP + t];
        else if (t < 128) fu[t] = ws[WS_US + t-64];
        else if (t < 160) fu[t] = ws[WS_UW + t-128];
        __syncthreads();
        if (t < 128) fu[160 + t] = cs[t] / (cs[128] * (float)N_COLL);
        __syncthreads();
        float acc = bf1[t];
        for (int k = 0; k < 288; ++k) acc = fmaf(fu[k], Wf1[k*256+t], acc);
        hid[t] = celu1(acc);
        __syncthreads();
        if (t < 128){
            float a2 = bf2[t];
            for (int k = 0; k < 256; ++k) a2 = fmaf(hid[k], Wf2[k*128+t], a2);
            ws[WS_XU + t] = celu1(a2);
        }
    }
    gbar(ws, 1);

    // =================== P2: GAT-1 flash attention (all 512 blocks) ===================
    {
        float* Cs = smem;          // [4][16][32] = 2048
        float* Sp = smem + 2048;   // [4][16]
        int w = wv;
        int rt = b >> 2, h = b & 3;
        int row = rt*16 + c16;
        const unsigned* mb = (const unsigned*)(ws + WS_MASK) + row*64;
        const unsigned short* HT = (const unsigned short*)(ws + WS_HT1) + h*32*2048;
        float f1 = ws[WS_F1G + (h<<11) + row];
        const float* f2 = ws + WS_F2G + (h<<11);
        f32x4 c0 = {0,0,0,0}, c1 = {0,0,0,0};
        float S = 0.f;
        for (int kt = w*16; kt < w*16 + 16; ++kt){
            unsigned m32 = mb[kt];
            const float* f2p = f2 + kt*32 + q*8;
            f32x4 fa = *(const f32x4*)(f2p);
            f32x4 fb = *(const f32x4*)(f2p+4);
            bf16x8 A;
            #pragma unroll
            for (int j = 0; j < 8; ++j){
                float e = f1 + ((j<4) ? fa[j] : fb[j-4]);
                e = fmaxf(e, 0.2f*e);
                float p = ((m32 >> (q*8+j)) & 1u) ? __expf(e) : 0.f;
                unsigned short pb = (unsigned short)(__float_as_uint(p) >> 16);
                A[j] = (short)pb;
                S += __uint_as_float(((unsigned)pb) << 16);
            }
            bf16x8 B0 = *(const bf16x8*)(HT + (c16)*2048    + kt*32 + q*8);
            bf16x8 B1 = *(const bf16x8*)(HT + (16+c16)*2048 + kt*32 + q*8);
            c0 = __builtin_amdgcn_mfma_f32_16x16x32_bf16(A, B0, c0, 0,0,0);
            c1 = __builtin_amdgcn_mfma_f32_16x16x32_bf16(A, B1, c1, 0,0,0);
        }
        S += __shfl_xor(S, 16);
        S += __shfl_xor(S, 32);
        if (q == 0) Sp[w*16 + c16] = S;
        #pragma unroll
        for (int r = 0; r < 4; ++r){
            Cs[w*512 + (q*4+r)*32 + c16]      = c0[r];
            Cs[w*512 + (q*4+r)*32 + 16 + c16] = c1[r];
        }
        __syncthreads();
        for (int ee = t; ee < 512; ee += 256){
            int r = ee >> 5, cc = ee & 31;
            float v = Cs[r*32+cc] + Cs[512 + r*32+cc] + Cs[1024 + r*32+cc] + Cs[1536 + r*32+cc];
            float Ss = Sp[r] + Sp[16+r] + Sp[32+r] + Sp[48+r];
            ws[WS_HCAT + (rt*16 + r)*128 + h*32 + cc] = celu1(v / Ss);
        }
    }
    gbar(ws, 2);

    // =================== P3 ===================
    if (b < 128){
        // ---- l2 projection via MFMA: block = 16 rows, wave = 32-col slab ----
        int rt = b, w = wv;
        bf16x8 A[4];
        const float* hcr = ws + WS_HCAT + (rt*16 + c16)*128;
        #pragma unroll
        for (int kt = 0; kt < 4; ++kt)
            A[kt] = pack8(*(const f32x4*)(hcr + kt*32 + q*8),
                          *(const f32x4*)(hcr + kt*32 + q*8 + 4));
        unsigned short* ht = (unsigned short*)(ws + WS_HT2);
        float f1p[4] = {0,0,0,0}, f2p[4] = {0,0,0,0};
        #pragma unroll
        for (int ct = 0; ct < 2; ++ct){
            int col = w*32 + ct*16 + c16;
            f32x4 c = {0,0,0,0};
            #pragma unroll
            for (int kt = 0; kt < 4; ++kt){
                bf16x8 Bf;
                #pragma unroll
                for (int j = 0; j < 8; ++j)
                    Bf[j] = f2bf(Wo[(kt*32 + q*8 + j)*128 + col]);
                c = __builtin_amdgcn_mfma_f32_16x16x32_bf16(A[kt], Bf, c, 0,0,0);
            }
            s16x4 pk;
            pk[0]=f2bf(c[0]); pk[1]=f2bf(c[1]); pk[2]=f2bf(c[2]); pk[3]=f2bf(c[3]);
            *(s16x4*)(ht + col*2048 + rt*16 + q*4) = pk;
            float aoa = ao[col], aob = ao[128 + col];
            #pragma unroll
            for (int r = 0; r < 4; ++r){
                f1p[r] = fmaf(c[r], aoa, f1p[r]);
                f2p[r] = fmaf(c[r], aob, f2p[r]);
            }
        }
        #pragma unroll
        for (int d = 1; d < 16; d <<= 1){
            #pragma unroll
            for (int r = 0; r < 4; ++r){
                f1p[r] += __shfl_xor(f1p[r], d);
                f2p[r] += __shfl_xor(f2p[r], d);
            }
        }
        if (c16 == 0){
            #pragma unroll
            for (int r = 0; r < 4; ++r){
                smem[w*16 + q*4 + r]      = f1p[r];
                smem[64 + w*16 + q*4 + r] = f2p[r];
            }
        }
        __syncthreads();
        if (t < 16){
            float s = smem[t] + smem[16+t] + smem[32+t] + smem[48+t];
            float u = smem[64+t] + smem[80+t] + smem[96+t] + smem[112+t];
            ws[WS_F1O + rt*16 + t] = s;
            ws[WS_F2O + rt*16 + t] = u;
        }
    } else if (b < 193){
        // ---- hypernetwork weights ----
        float* xu = smem;
        if (t < 128) xu[t] = ws[WS_XU + t];
        __syncthreads();
        int j = (b - 128)*256 + t;
        if (j < 14336){
            float acc = bm1[j];
            for (int k = 0; k < 128; ++k) acc = fmaf(xu[k], Wm1[k*14336 + j], acc);
            ws[WS_W1 + j] = celu1(acc);
        } else if (j < 16384){
            int j2 = j - 14336;
            float acc = bm2[j2];
            for (int k = 0; k < 128; ++k) acc = fmaf(xu[k], Wm2[k*2048 + j2], acc);
            ws[WS_W2 + j2] = celu1(acc);
        } else if (j < 16416){
            int j3 = j - 16384;
            float acc = bm3[j3];
            for (int k = 0; k < 128; ++k) acc = fmaf(xu[k], Wm3[k*32 + j3], acc);
            ws[WS_W3 + j3] = celu1(acc);
        }
    }
    gbar(ws, 3);

    // =================== P4: GAT-2 flash attention + banked column mean ===================
    if (b < 128){
        float* Cs   = smem;          // [4][16][128] = 8192
        float* Sp   = smem + 8192;   // 64
        float* colp = smem + 8256;   // 256
        int w = wv;
        int rt = b;
        int row = rt*16 + c16;
        const unsigned* mb = (const unsigned*)(ws + WS_MASK) + row*64;
        const unsigned short* HT = (const unsigned short*)(ws + WS_HT2);
        float f1 = ws[WS_F1O + row];
        const float* f2 = ws + WS_F2O;
        f32x4 c[8];
        #pragma unroll
        for (int nt = 0; nt < 8; ++nt) c[nt] = (f32x4){0,0,0,0};
        float S = 0.f;
        for (int kt = w*16; kt < w*16 + 16; ++kt){
            unsigned m32 = mb[kt];
            const float* f2p = f2 + kt*32 + q*8;
            f32x4 fa = *(const f32x4*)(f2p);
            f32x4 fb = *(const f32x4*)(f2p+4);
            bf16x8 A;
            #pragma unroll
            for (int j = 0; j < 8; ++j){
                float e = f1 + ((j<4) ? fa[j] : fb[j-4]);
                e = fmaxf(e, 0.2f*e);
                float p = ((m32 >> (q*8+j)) & 1u) ? __expf(e) : 0.f;
                unsigned short pb = (unsigned short)(__float_as_uint(p) >> 16);
                A[j] = (short)pb;
                S += __uint_as_float(((unsigned)pb) << 16);
            }
            #pragma unroll
            for (int nt = 0; nt < 8; ++nt){
                bf16x8 B = *(const bf16x8*)(HT + (nt*16 + c16)*2048 + kt*32 + q*8);
                c[nt] = __builtin_amdgcn_mfma_f32_16x16x32_bf16(A, B, c[nt], 0,0,0);
            }
        }
        S += __shfl_xor(S, 16);
        S += __shfl_xor(S, 32);
        if (q == 0) Sp[w*16 + c16] = S;
        #pragma unroll
        for (int nt = 0; nt < 8; ++nt)
            #pragma unroll
            for (int r = 0; r < 4; ++r)
                Cs[w*2048 + (q*4+r)*128 + nt*16 + c16] = c[nt][r];
        __syncthreads();
        int col = t & 127, half = t >> 7;
        float part = 0.f;
        for (int r = half*8; r < half*8 + 8; ++r){
            float v = Cs[r*128+col] + Cs[2048 + r*128+col] + Cs[4096 + r*128+col] + Cs[6144 + r*128+col];
            float Ss = Sp[r] + Sp[16+r] + Sp[32+r] + Sp[48+r];
            part += celu1(v / Ss);
        }
        colp[half*128 + col] = part;
        __syncthreads();
        if (t < 128) atomicAdd(ws + WS_NEIGH + (b & 15)*128 + t, colp[t] + colp[128+t]);
    }
    gbar(ws, 4);

    // =================== P5: final meta-MLP + sigmoid ===================
    if (b == 0){
        float* xh = smem;        // 224
        float* r1 = smem + 224;  // 64
        float* r2 = smem + 288;  // 32
        if (t < 32)       xh[t]      = ws[WS_HP + t];
        else if (t < 64)  xh[t]      = ws[WS_HV + t-32];
        else if (t < 96)  xh[t]      = ws[WS_HR + t-64];
        if (t < 128){
            float s = 0.f;
            #pragma unroll
            for (int k = 0; k < 16; ++k) s += ws[WS_NEIGH + k*128 + t];
            xh[96 + t] = s * (1.f/2048.f);
        }
        __syncthreads();
        if (t < 64){
            float acc = 0.f;
            for (int k = 0; k < 224; ++k) acc = fmaf(xh[k], ws[WS_W1 + k*64 + t], acc);
            r1[t] = fmaxf(acc, 0.f);
        }
        __syncthreads();
        if (t < 32){
            float acc = 0.f;
            for (int k = 0; k < 64; ++k) acc = fmaf(r1[k], ws[WS_W2 + k*32 + t], acc);
            r2[t] = fmaxf(acc, 0.f);
        }
        __syncthreads();
        if (t == 0){
            float acc = 0.f;
            for (int k = 0; k < 32; ++k) acc = fmaf(r2[k], ws[WS_W3 + k], acc);
            out[0] = 1.f / (1.f + __expf(-acc));
        }
    }
}

// ---------------- launcher ----------------
extern "C" void kernel_launch(void* const* d_in, const int* in_sizes, int n_in,
                              void* d_out, int out_size, void* d_ws, size_t ws_size,
                              hipStream_t stream)
{
    fp xup = (fp)d_in[0],  xus = (fp)d_in[1],  xuw = (fp)d_in[2];
    fp Xcp = (fp)d_in[3],  Xcs = (fp)d_in[4];
    fp xhp = (fp)d_in[5],  xhv = (fp)d_in[6],  xhr = (fp)d_in[7];
    fp Xnp = (fp)d_in[8],  Xns = (fp)d_in[9];
    const int* adj = (const int*)d_in[10];
    fp Wup = (fp)d_in[11], bup = (fp)d_in[12];
    fp Wus = (fp)d_in[13], bus = (fp)d_in[14];
    fp Wuw = (fp)d_in[15], buw = (fp)d_in[16];
    fp vw  = (fp)d_in[17];
    fp Wf1 = (fp)d_in[18], bf1 = (fp)d_in[19];
    fp Wf2 = (fp)d_in[20], bf2 = (fp)d_in[21];
    fp Wm1 = (fp)d_in[22], bm1 = (fp)d_in[23];
    fp Wm2 = (fp)d_in[24], bm2 = (fp)d_in[25];
    fp Wm3 = (fp)d_in[26], bm3 = (fp)d_in[27];
    fp Whp = (fp)d_in[28], bhp = (fp)d_in[29];
    fp Whv = (fp)d_in[30], bhv = (fp)d_in[31];
    fp Whr = (fp)d_in[32], bhr = (fp)d_in[33];
    fp Wg  = (fp)d_in[34], ag  = (fp)d_in[35];
    fp Wo  = (fp)d_in[36], ao  = (fp)d_in[37];
    float* ws = (float*)d_ws;
    float* out = (float*)d_out;

    // zero NEIGH(16x128) + CSUM(32x132) + BAR(8): 16928..23208
    hipMemsetAsync((char*)d_ws + WS_NEIGH*sizeof(float), 0, 6280*sizeof(float), stream);

    mega<<<GRID_N, 256, 0, stream>>>(
        xup,xus,xuw,Xcp,Xcs, xhp,xhv,xhr,Xnp,Xns, adj,
        Wup,bup,Wus,bus,Wuw,buw,vw,
        Wf1,bf1,Wf2,bf2, Wm1,bm1,Wm2,bm2,Wm3,bm3,
        Whp,bhp,Whv,bhv,Whr,bhr, Wg,ag,Wo,ao, ws, out);
}

// Round 8
// 288.633 us; speedup vs baseline: 1.7268x; 1.7268x over previous
//
#include <hip/hip_runtime.h>
#include <math.h>

#define N_COLL 200000

typedef const float* fp;
typedef __attribute__((ext_vector_type(8))) short bf16x8;
typedef __attribute__((ext_vector_type(4))) float f32x4;
typedef __attribute__((ext_vector_type(4))) short s16x4;

// ---------------- workspace layout (float offsets) ----------------
#define WS_UP    0         // 64
#define WS_US    64        // 64
#define WS_UW    128       // 32
#define WS_HP    160       // 32
#define WS_HV    192       // 32
#define WS_HR    224       // 32
#define WS_XU    384       // 128
#define WS_W1    512       // 14336
#define WS_W2    14848     // 2048
#define WS_W3    16896     // 32
#define WS_NEIGH 16928     // 16 banks x 128 (zeroed)
#define WS_CSUM  18976     // 32 banks x 132 (zeroed)
#define WS_GX    23552     // 2048*128 f32
#define WS_HT1   285696    // 128*2048 u16
#define WS_F1G   416768    // 4*2048
#define WS_F2G   424960    // 4*2048
#define WS_HCAT  433152    // 2048*128 f32
#define WS_HT2   695296    // 128*2048 u16
#define WS_F1O   826368    // 2048
#define WS_F2O   828416    // 2048
#define WS_MASK  830464    // 2048*64 u32
// end 961536 floats = 3.85 MB

__device__ __forceinline__ float celu1(float x){
    return fmaxf(x, 0.f) + __expf(fminf(x, 0.f)) - 1.f;   // branchless elu
}
__device__ __forceinline__ float rl(float x, int k){
    return __int_as_float(__builtin_amdgcn_readlane(__float_as_int(x), k));
}
__device__ __forceinline__ short f2bf(float f){
    return (short)(__float_as_uint(f) >> 16);
}
__device__ __forceinline__ bf16x8 pack8(f32x4 a, f32x4 b){
    bf16x8 r;
    r[0]=f2bf(a[0]); r[1]=f2bf(a[1]); r[2]=f2bf(a[2]); r[3]=f2bf(a[3]);
    r[4]=f2bf(b[0]); r[5]=f2bf(b[1]); r[6]=f2bf(b[2]); r[7]=f2bf(b[3]);
    return r;
}

// ============ kA: coll(0-1023) | mask(1024-1279) | gx(1280-1407) | tiny(1408) ============
__global__ __launch_bounds__(256) void kA(
    fp Xcp, fp Xcs, fp vw,
    fp xup, fp xus, fp xuw, fp xhp, fp xhv, fp xhr,
    fp Wup, fp bup, fp Wus, fp bus, fp Wuw, fp buw,
    fp Whp, fp bhp, fp Whv, fp bhv, fp Whr, fp bhr,
    fp Xnp, fp Xns, const int* __restrict__ adj, float* ws)
{
    __shared__ float sRed[528];
    const int t = threadIdx.x;
    const int b = blockIdx.x;
    const int lane = t & 63, wv = t >> 6;
    const int q = lane >> 4, c16 = lane & 15;
    if (b < 1024){
        // ---- colleague bf16-MFMA pass; B-frags direct from global ----
        bf16x8 B[2][2][4];
        float bias[8], vv[8];
        #pragma unroll
        for (int mat = 0; mat < 2; ++mat){
            fp W = mat ? Wus : Wup;
            #pragma unroll
            for (int ks = 0; ks < 2; ++ks)
                #pragma unroll
                for (int ct = 0; ct < 4; ++ct){
                    bf16x8 f;
                    #pragma unroll
                    for (int j = 0; j < 8; ++j)
                        f[j] = f2bf(W[(ks*32 + q*8 + j)*64 + ct*16 + c16]);
                    B[mat][ks][ct] = f;
                }
        }
        #pragma unroll
        for (int tt = 0; tt < 8; ++tt){
            int gcol = tt*16 + c16;
            bias[tt] = (tt < 4) ? bup[gcol] : bus[gcol-64];
            vv[tt]   = vw[128 + gcol];
        }
        const int wave = b*4 + wv;          // 0..4095
        float accw[8] = {0,0,0,0,0,0,0,0};
        float accl = 0.f;
        int rt = wave;
        f32x4 L[8];
        {
            int row = rt*16 + c16;
            const float* xp = Xcp + row*64 + q*8;
            const float* xs = Xcs + row*64 + q*8;
            L[0]=*(const f32x4*)(xp);    L[1]=*(const f32x4*)(xp+4);
            L[2]=*(const f32x4*)(xp+32); L[3]=*(const f32x4*)(xp+36);
            L[4]=*(const f32x4*)(xs);    L[5]=*(const f32x4*)(xs+4);
            L[6]=*(const f32x4*)(xs+32); L[7]=*(const f32x4*)(xs+36);
        }
        while (rt < 12500){
            int nrt = rt + 4096;
            f32x4 N[8];
            if (nrt < 12500){
                int row = nrt*16 + c16;
                const float* xp = Xcp + row*64 + q*8;
                const float* xs = Xcs + row*64 + q*8;
                N[0]=*(const f32x4*)(xp);    N[1]=*(const f32x4*)(xp+4);
                N[2]=*(const f32x4*)(xp+32); N[3]=*(const f32x4*)(xp+36);
                N[4]=*(const f32x4*)(xs);    N[5]=*(const f32x4*)(xs+4);
                N[6]=*(const f32x4*)(xs+32); N[7]=*(const f32x4*)(xs+36);
            }
            bf16x8 Ap0 = pack8(L[0],L[1]);
            bf16x8 Ap1 = pack8(L[2],L[3]);
            bf16x8 As0 = pack8(L[4],L[5]);
            bf16x8 As1 = pack8(L[6],L[7]);
            float cel[8][4];
            float logit[4] = {0,0,0,0};
            #pragma unroll
            for (int tt = 0; tt < 8; ++tt){
                int ct = tt & 3;
                f32x4 c = {0.f,0.f,0.f,0.f};
                if (tt < 4){
                    c = __builtin_amdgcn_mfma_f32_16x16x32_bf16(Ap0, B[0][0][ct], c, 0,0,0);
                    c = __builtin_amdgcn_mfma_f32_16x16x32_bf16(Ap1, B[0][1][ct], c, 0,0,0);
                } else {
                    c = __builtin_amdgcn_mfma_f32_16x16x32_bf16(As0, B[1][0][ct], c, 0,0,0);
                    c = __builtin_amdgcn_mfma_f32_16x16x32_bf16(As1, B[1][1][ct], c, 0,0,0);
                }
                #pragma unroll
                for (int r = 0; r < 4; ++r){
                    float v = celu1(c[r] + bias[tt]);
                    cel[tt][r] = v;
                    logit[r] = fmaf(v, vv[tt], logit[r]);
                }
            }
            #pragma unroll
            for (int d = 1; d < 16; d <<= 1){
                #pragma unroll
                for (int r = 0; r < 4; ++r) logit[r] += __shfl_xor(logit[r], d);
            }
            float p[4];
            #pragma unroll
            for (int r = 0; r < 4; ++r){ p[r] = __expf(logit[r]); accl += p[r]; }
            #pragma unroll
            for (int tt = 0; tt < 8; ++tt)
                #pragma unroll
                for (int r = 0; r < 4; ++r) accw[tt] = fmaf(p[r], cel[tt][r], accw[tt]);
            #pragma unroll
            for (int i = 0; i < 8; ++i) L[i] = N[i];
            rt = nrt;
        }
        #pragma unroll
        for (int tt = 0; tt < 8; ++tt){
            accw[tt] += __shfl_xor(accw[tt], 16);
            accw[tt] += __shfl_xor(accw[tt], 32);
        }
        accl += __shfl_xor(accl, 16);
        accl += __shfl_xor(accl, 32);
        if (q == 0){
            #pragma unroll
            for (int tt = 0; tt < 8; ++tt) sRed[wv*132 + tt*16 + c16] = accw[tt];
        }
        if (lane == 0) sRed[wv*132 + 128] = accl;
        __syncthreads();
        if (t < 129){
            float s = sRed[t] + sRed[132+t] + sRed[264+t] + sRed[396+t];
            atomicAdd(ws + WS_CSUM + (b & 31)*132 + t, s);
        }
    } else if (b < 1280){
        // ---- adjacency -> bitmask (256 blocks x 512 words) ----
        unsigned* mb = (unsigned*)(ws + WS_MASK);
        #pragma unroll
        for (int s = 0; s < 2; ++s){
            int idx = (b-1024)*512 + s*256 + t;
            const int* a = adj + (idx>>6)*2048 + (idx&63)*32;
            unsigned bits = 0u;
            #pragma unroll 8
            for (int j = 0; j < 32; ++j) bits |= (a[j] > 0 ? 1u : 0u) << j;
            mb[idx] = bits;
        }
    } else if (b < 1408){
        // ---- gx embeds, W direct from global/L2 ----
        int wave = ((b-1280)<<2) | wv;       // 0..511
        for (int r = wave; r < 2048; r += 512){
            float xp = Xnp[(r<<6)+lane], xs = Xns[(r<<6)+lane];
            float cp = bup[lane], cs = bus[lane];
            #pragma unroll 8
            for (int k = 0; k < 64; ++k){
                cp = fmaf(rl(xp,k), Wup[(k<<6)+lane], cp);
                cs = fmaf(rl(xs,k), Wus[(k<<6)+lane], cs);
            }
            ws[WS_GX + (r<<7) + lane]      = celu1(cp);
            ws[WS_GX + (r<<7) + 64 + lane] = celu1(cs);
        }
    } else {
        // ---- tiny user/house embeddings ----
        if (t < 64){
            float acc = bup[t];
            for (int k = 0; k < 64; ++k) acc = fmaf(xup[k], Wup[k*64+t], acc);
            ws[WS_UP+t] = celu1(acc);
        } else if (t < 128){
            int j = t-64; float acc = bus[j];
            for (int k = 0; k < 64; ++k) acc = fmaf(xus[k], Wus[k*64+j], acc);
            ws[WS_US+j] = celu1(acc);
        } else if (t < 160){
            int j = t-128; float acc = buw[j];
            for (int k = 0; k < 32; ++k) acc = fmaf(xuw[k], Wuw[k*32+j], acc);
            ws[WS_UW+j] = celu1(acc);
        } else if (t < 192){
            int j = t-160; float acc = bhp[j];
            for (int k = 0; k < 32; ++k) acc = fmaf(xhp[k], Whp[k*32+j], acc);
            ws[WS_HP+j] = celu1(acc);
        } else if (t < 224){
            int j = t-192; float acc = bhv[j];
            for (int k = 0; k < 32; ++k) acc = fmaf(xhv[k], Whv[k*32+j], acc);
            ws[WS_HV+j] = celu1(acc);
        } else {
            int j = t-224; float acc = bhr[j];
            for (int k = 0; k < 32; ++k) acc = fmaf(xhr[k], Whr[k*32+j], acc);
            ws[WS_HR+j] = celu1(acc);
        }
    }
}

// ============ kB: MFMA l1_proj (0-127) | fuse_user (128) ============
__global__ __launch_bounds__(256) void kB(fp Wg, fp ag, fp Wf1, fp bf1, fp Wf2, fp bf2, float* ws){
    __shared__ float smem[673];
    const int t = threadIdx.x;
    const int b = blockIdx.x;
    const int lane = t & 63, wv = t >> 6;
    const int q = lane >> 4, c16 = lane & 15;
    if (b < 128){
        int rt = b, w = wv;     // wave = head
        bf16x8 A[4];
        const float* gxr = ws + WS_GX + (rt*16 + c16)*128;
        #pragma unroll
        for (int kt = 0; kt < 4; ++kt)
            A[kt] = pack8(*(const f32x4*)(gxr + kt*32 + q*8),
                          *(const f32x4*)(gxr + kt*32 + q*8 + 4));
        unsigned short* ht = (unsigned short*)(ws + WS_HT1);
        float f1p[4] = {0,0,0,0}, f2p[4] = {0,0,0,0};
        #pragma unroll
        for (int ct = 0; ct < 2; ++ct){
            int g = ct*16 + c16;
            f32x4 c = {0,0,0,0};
            #pragma unroll
            for (int kt = 0; kt < 4; ++kt){
                bf16x8 Bf;
                #pragma unroll
                for (int j = 0; j < 8; ++j)
                    Bf[j] = f2bf(Wg[w*4096 + (kt*32 + q*8 + j)*32 + g]);
                c = __builtin_amdgcn_mfma_f32_16x16x32_bf16(A[kt], Bf, c, 0,0,0);
            }
            int col = w*32 + g;
            s16x4 pk;
            pk[0]=f2bf(c[0]); pk[1]=f2bf(c[1]); pk[2]=f2bf(c[2]); pk[3]=f2bf(c[3]);
            *(s16x4*)(ht + col*2048 + rt*16 + q*4) = pk;
            float aga = ag[w*64 + g], agb = ag[w*64 + 32 + g];
            #pragma unroll
            for (int r = 0; r < 4; ++r){
                f1p[r] = fmaf(c[r], aga, f1p[r]);
                f2p[r] = fmaf(c[r], agb, f2p[r]);
            }
        }
        #pragma unroll
        for (int d = 1; d < 16; d <<= 1){
            #pragma unroll
            for (int r = 0; r < 4; ++r){
                f1p[r] += __shfl_xor(f1p[r], d);
                f2p[r] += __shfl_xor(f2p[r], d);
            }
        }
        if (c16 == 0){
            #pragma unroll
            for (int r = 0; r < 4; ++r){
                ws[WS_F1G + (w<<11) + rt*16 + q*4 + r] = f1p[r];
                ws[WS_F2G + (w<<11) + rt*16 + q*4 + r] = f2p[r];
            }
        }
    } else {
        float* fu  = smem;        // 288
        float* hid = smem + 288;  // 256
        float* cs  = smem + 544;  // 129
        if (t < 129){
            float s = 0.f;
            #pragma unroll
            for (int k = 0; k < 32; ++k) s += ws[WS_CSUM + k*132 + t];
            cs[t] = s;
        }
        if (t < 64)       fu[t] = ws[WS_UP + t];
        else if (t < 128) fu[t] = ws[WS_US + t-64];
        else if (t < 160) fu[t] = ws[WS_UW + t-128];
        __syncthreads();
        if (t < 128) fu[160 + t] = cs[t] / (cs[128] * (float)N_COLL);
        __syncthreads();
        float acc = bf1[t];
        for (int k = 0; k < 288; ++k) acc = fmaf(fu[k], Wf1[k*256+t], acc);
        hid[t] = celu1(acc);
        __syncthreads();
        if (t < 128){
            float a2 = bf2[t];
            for (int k = 0; k < 256; ++k) a2 = fmaf(hid[k], Wf2[k*128+t], a2);
            ws[WS_XU + t] = celu1(a2);
        }
    }
}

// ============ kC: attend1 (0-511) | hyper_w (512-576) ============
__global__ __launch_bounds__(256) void kC(fp Wm1, fp bm1, fp Wm2, fp bm2, fp Wm3, fp bm3, float* ws){
    __shared__ float smem[2112];
    const int t = threadIdx.x;
    const int b = blockIdx.x;
    const int lane = t & 63, wv = t >> 6;
    const int q = lane >> 4, c16 = lane & 15;
    if (b < 512){
        float* Cs = smem;          // [4][16][32]
        float* Sp = smem + 2048;   // [4][16]
        int w = wv;
        int rt = b >> 2, h = b & 3;
        int row = rt*16 + c16;
        const unsigned* mb = (const unsigned*)(ws + WS_MASK) + row*64;
        const unsigned short* HT = (const unsigned short*)(ws + WS_HT1) + h*32*2048;
        float f1 = ws[WS_F1G + (h<<11) + row];
        const float* f2 = ws + WS_F2G + (h<<11);
        f32x4 c0 = {0,0,0,0}, c1 = {0,0,0,0};
        float S = 0.f;
        for (int kt = w*16; kt < w*16 + 16; ++kt){
            unsigned m32 = mb[kt];
            const float* f2p = f2 + kt*32 + q*8;
            f32x4 fa = *(const f32x4*)(f2p);
            f32x4 fb = *(const f32x4*)(f2p+4);
            bf16x8 A;
            #pragma unroll
            for (int j = 0; j < 8; ++j){
                float e = f1 + ((j<4) ? fa[j] : fb[j-4]);
                e = fmaxf(e, 0.2f*e);
                float p = ((m32 >> (q*8+j)) & 1u) ? __expf(e) : 0.f;
                unsigned short pb = (unsigned short)(__float_as_uint(p) >> 16);
                A[j] = (short)pb;
                S += __uint_as_float(((unsigned)pb) << 16);
            }
            bf16x8 B0 = *(const bf16x8*)(HT + (c16)*2048    + kt*32 + q*8);
            bf16x8 B1 = *(const bf16x8*)(HT + (16+c16)*2048 + kt*32 + q*8);
            c0 = __builtin_amdgcn_mfma_f32_16x16x32_bf16(A, B0, c0, 0,0,0);
            c1 = __builtin_amdgcn_mfma_f32_16x16x32_bf16(A, B1, c1, 0,0,0);
        }
        S += __shfl_xor(S, 16);
        S += __shfl_xor(S, 32);
        if (q == 0) Sp[w*16 + c16] = S;
        #pragma unroll
        for (int r = 0; r < 4; ++r){
            Cs[w*512 + (q*4+r)*32 + c16]      = c0[r];
            Cs[w*512 + (q*4+r)*32 + 16 + c16] = c1[r];
        }
        __syncthreads();
        for (int ee = t; ee < 512; ee += 256){
            int r = ee >> 5, cc = ee & 31;
            float v = Cs[r*32+cc] + Cs[512 + r*32+cc] + Cs[1024 + r*32+cc] + Cs[1536 + r*32+cc];
            float Ss = Sp[r] + Sp[16+r] + Sp[32+r] + Sp[48+r];
            ws[WS_HCAT + (rt*16 + r)*128 + h*32 + cc] = celu1(v / Ss);
        }
    } else {
        float* xu = smem;
        if (t < 128) xu[t] = ws[WS_XU + t];
        __syncthreads();
        int j = (b - 512)*256 + t;
        if (j < 14336){
            float acc = bm1[j];
            for (int k = 0; k < 128; ++k) acc = fmaf(xu[k], Wm1[k*14336 + j], acc);
            ws[WS_W1 + j] = celu1(acc);
        } else if (j < 16384){
            int j2 = j - 14336;
            float acc = bm2[j2];
            for (int k = 0; k < 128; ++k) acc = fmaf(xu[k], Wm2[k*2048 + j2], acc);
            ws[WS_W2 + j2] = celu1(acc);
        } else if (j < 16416){
            int j3 = j - 16384;
            float acc = bm3[j3];
            for (int k = 0; k < 128; ++k) acc = fmaf(xu[k], Wm3[k*32 + j3], acc);
            ws[WS_W3 + j3] = celu1(acc);
        }
    }
}

// ============ kD: MFMA l2_proj (128 blocks) ============
__global__ __launch_bounds__(256) void kD(fp Wo, fp ao, float* ws){
    __shared__ float smem[128];
    const int t = threadIdx.x;
    const int lane = t & 63, wv = t >> 6;
    const int q = lane >> 4, c16 = lane & 15;
    int rt = blockIdx.x, w = wv;
    bf16x8 A[4];
    const float* hcr = ws + WS_HCAT + (rt*16 + c16)*128;
    #pragma unroll
    for (int kt = 0; kt < 4; ++kt)
        A[kt] = pack8(*(const f32x4*)(hcr + kt*32 + q*8),
                      *(const f32x4*)(hcr + kt*32 + q*8 + 4));
    unsigned short* ht = (unsigned short*)(ws + WS_HT2);
    float f1p[4] = {0,0,0,0}, f2p[4] = {0,0,0,0};
    #pragma unroll
    for (int ct = 0; ct < 2; ++ct){
        int col = w*32 + ct*16 + c16;
        f32x4 c = {0,0,0,0};
        #pragma unroll
        for (int kt = 0; kt < 4; ++kt){
            bf16x8 Bf;
            #pragma unroll
            for (int j = 0; j < 8; ++j)
                Bf[j] = f2bf(Wo[(kt*32 + q*8 + j)*128 + col]);
            c = __builtin_amdgcn_mfma_f32_16x16x32_bf16(A[kt], Bf, c, 0,0,0);
        }
        s16x4 pk;
        pk[0]=f2bf(c[0]); pk[1]=f2bf(c[1]); pk[2]=f2bf(c[2]); pk[3]=f2bf(c[3]);
        *(s16x4*)(ht + col*2048 + rt*16 + q*4) = pk;
        float aoa = ao[col], aob = ao[128 + col];
        #pragma unroll
        for (int r = 0; r < 4; ++r){
            f1p[r] = fmaf(c[r], aoa, f1p[r]);
            f2p[r] = fmaf(c[r], aob, f2p[r]);
        }
    }
    #pragma unroll
    for (int d = 1; d < 16; d <<= 1){
        #pragma unroll
        for (int r = 0; r < 4; ++r){
            f1p[r] += __shfl_xor(f1p[r], d);
            f2p[r] += __shfl_xor(f2p[r], d);
        }
    }
    if (c16 == 0){
        #pragma unroll
        for (int r = 0; r < 4; ++r){
            smem[w*16 + q*4 + r]      = f1p[r];
            smem[64 + w*16 + q*4 + r] = f2p[r];
        }
    }
    __syncthreads();
    if (t < 16){
        float s = smem[t] + smem[16+t] + smem[32+t] + smem[48+t];
        float u = smem[64+t] + smem[80+t] + smem[96+t] + smem[112+t];
        ws[WS_F1O + rt*16 + t] = s;
        ws[WS_F2O + rt*16 + t] = u;
    }
}

// ============ kE: attend2 split (256 blocks: 16 rows x 64 cols each) ============
__global__ __launch_bounds__(256) void kE(float* ws){
    __shared__ float Cs[4][16][64];   // 4096
    __shared__ float Sp[4][16];
    __shared__ float colp[4][64];
    const int t = threadIdx.x;
    const int lane = t & 63, wv = t >> 6;
    const int q = lane >> 4, c16 = lane & 15;
    int rt = blockIdx.x >> 1, half = blockIdx.x & 1;
    int w = wv;
    int row = rt*16 + c16;
    const unsigned* mb = (const unsigned*)(ws + WS_MASK) + row*64;
    const unsigned short* HT = (const unsigned short*)(ws + WS_HT2);
    float f1 = ws[WS_F1O + row];
    const float* f2 = ws + WS_F2O;
    f32x4 c[4];
    #pragma unroll
    for (int nt = 0; nt < 4; ++nt) c[nt] = (f32x4){0,0,0,0};
    float S = 0.f;
    for (int kt = w*16; kt < w*16 + 16; ++kt){
        unsigned m32 = mb[kt];
        const float* f2p = f2 + kt*32 + q*8;
        f32x4 fa = *(const f32x4*)(f2p);
        f32x4 fb = *(const f32x4*)(f2p+4);
        bf16x8 A;
        #pragma unroll
        for (int j = 0; j < 8; ++j){
            float e = f1 + ((j<4) ? fa[j] : fb[j-4]);
            e = fmaxf(e, 0.2f*e);
            float p = ((m32 >> (q*8+j)) & 1u) ? __expf(e) : 0.f;
            unsigned short pb = (unsigned short)(__float_as_uint(p) >> 16);
            A[j] = (short)pb;
            S += __uint_as_float(((unsigned)pb) << 16);
        }
        #pragma unroll
        for (int nt = 0; nt < 4; ++nt){
            int col16 = half*4 + nt;
            bf16x8 B = *(const bf16x8*)(HT + (col16*16 + c16)*2048 + kt*32 + q*8);
            c[nt] = __builtin_amdgcn_mfma_f32_16x16x32_bf16(A, B, c[nt], 0,0,0);
        }
    }
    S += __shfl_xor(S, 16);
    S += __shfl_xor(S, 32);
    if (q == 0) Sp[w][c16] = S;
    #pragma unroll
    for (int nt = 0; nt < 4; ++nt)
        #pragma unroll
        for (int r = 0; r < 4; ++r)
            Cs[w][q*4+r][nt*16+c16] = c[nt][r];
    __syncthreads();
    int col = t & 63, grp = t >> 6;
    float part = 0.f;
    for (int r = grp*4; r < grp*4 + 4; ++r){
        float v = Cs[0][r][col] + Cs[1][r][col] + Cs[2][r][col] + Cs[3][r][col];
        float Ss = Sp[0][r] + Sp[1][r] + Sp[2][r] + Sp[3][r];
        part += celu1(v / Ss);
    }
    colp[grp][col] = part;
    __syncthreads();
    if (t < 64){
        float s = colp[0][t] + colp[1][t] + colp[2][t] + colp[3][t];
        atomicAdd(ws + WS_NEIGH + (blockIdx.x & 15)*128 + half*64 + t, s);
    }
}

// ============ kF: final meta-MLP + sigmoid ============
__global__ __launch_bounds__(256) void kF(float* ws, float* out){
    __shared__ float xh[224], r1[64], r2[32];
    int t = threadIdx.x;
    if (t < 32)       xh[t]      = ws[WS_HP + t];
    else if (t < 64)  xh[t]      = ws[WS_HV + t-32];
    else if (t < 96)  xh[t]      = ws[WS_HR + t-64];
    if (t < 128){
        float s = 0.f;
        #pragma unroll
        for (int k = 0; k < 16; ++k) s += ws[WS_NEIGH + k*128 + t];
        xh[96 + t] = s * (1.f/2048.f);
    }
    __syncthreads();
    if (t < 64){
        float acc = 0.f;
        for (int k = 0; k < 224; ++k) acc = fmaf(xh[k], ws[WS_W1 + k*64 + t], acc);
        r1[t] = fmaxf(acc, 0.f);
    }
    __syncthreads();
    if (t < 32){
        float acc = 0.f;
        for (int k = 0; k < 64; ++k) acc = fmaf(r1[k], ws[WS_W2 + k*32 + t], acc);
        r2[t] = fmaxf(acc, 0.f);
    }
    __syncthreads();
    if (t == 0){
        float acc = 0.f;
        for (int k = 0; k < 32; ++k) acc = fmaf(r2[k], ws[WS_W3 + k], acc);
        out[0] = 1.f / (1.f + __expf(-acc));
    }
}

// ---------------- launcher ----------------
extern "C" void kernel_launch(void* const* d_in, const int* in_sizes, int n_in,
                              void* d_out, int out_size, void* d_ws, size_t ws_size,
                              hipStream_t stream)
{
    fp xup = (fp)d_in[0],  xus = (fp)d_in[1],  xuw = (fp)d_in[2];
    fp Xcp = (fp)d_in[3],  Xcs = (fp)d_in[4];
    fp xhp = (fp)d_in[5],  xhv = (fp)d_in[6],  xhr = (fp)d_in[7];
    fp Xnp = (fp)d_in[8],  Xns = (fp)d_in[9];
    const int* adj = (const int*)d_in[10];
    fp Wup = (fp)d_in[11], bup = (fp)d_in[12];
    fp Wus = (fp)d_in[13], bus = (fp)d_in[14];
    fp Wuw = (fp)d_in[15], buw = (fp)d_in[16];
    fp vw  = (fp)d_in[17];
    fp Wf1 = (fp)d_in[18], bf1 = (fp)d_in[19];
    fp Wf2 = (fp)d_in[20], bf2 = (fp)d_in[21];
    fp Wm1 = (fp)d_in[22], bm1 = (fp)d_in[23];
    fp Wm2 = (fp)d_in[24], bm2 = (fp)d_in[25];
    fp Wm3 = (fp)d_in[26], bm3 = (fp)d_in[27];
    fp Whp = (fp)d_in[28], bhp = (fp)d_in[29];
    fp Whv = (fp)d_in[30], bhv = (fp)d_in[31];
    fp Whr = (fp)d_in[32], bhr = (fp)d_in[33];
    fp Wg  = (fp)d_in[34], ag  = (fp)d_in[35];
    fp Wo  = (fp)d_in[36], ao  = (fp)d_in[37];
    float* ws = (float*)d_ws;
    float* out = (float*)d_out;

    // zero NEIGH(16x128) + CSUM(32x132): contiguous 16928..23200
    hipMemsetAsync((char*)d_ws + WS_NEIGH*sizeof(float), 0, 6272*sizeof(float), stream);

    kA<<<1409, 256, 0, stream>>>(Xcp,Xcs,vw, xup,xus,xuw,xhp,xhv,xhr,
                                 Wup,bup,Wus,bus,Wuw,buw,Whp,bhp,Whv,bhv,Whr,bhr,
                                 Xnp,Xns, adj, ws);
    kB<<<129, 256, 0, stream>>>(Wg, ag, Wf1,bf1,Wf2,bf2, ws);
    kC<<<577, 256, 0, stream>>>(Wm1,bm1,Wm2,bm2,Wm3,bm3, ws);
    kD<<<128, 256, 0, stream>>>(Wo, ao, ws);
    kE<<<256, 256, 0, stream>>>(ws);
    kF<<<1, 256, 0, stream>>>(ws, out);
}